// Round 10
// baseline (99.309 us; speedup 1.0000x reference)
//
#include <hip/hip_runtime.h>

typedef unsigned short u16;
typedef unsigned int u32;
using short8 = __attribute__((ext_vector_type(8))) short;
using f32x4  = __attribute__((ext_vector_type(4))) float;
using i32x4  = __attribute__((ext_vector_type(4))) int;   // clang vector: OK for nontemporal builtin

#define NB 8
#define NN 2048

// k3 LDS: hi slab 64x1040B, lo slab 64x1040B, ed 2KB
#define ROWB    1040              // 512j*2B + 16 pad; b128 quarter-wave 2-way max
#define LO_OFF  66560             // 64*1040
#define ED_OFF  133120
#define SMEM_SZ 135168            // 132 KB -> 1 block/CU

__device__ __forceinline__ u16 f2bf(float f) {
    u32 u = __float_as_uint(f);
    u32 r = (u + 0x7fffu + ((u >> 16) & 1u)) >> 16;   // RNE
    return (u16)r;
}
__device__ __forceinline__ float bf2f(u16 h) {
    return __uint_as_float(((u32)h) << 16);
}
__device__ __forceinline__ u32 encf(float f) {
    u32 u = __float_as_uint(f);
    return (u & 0x80000000u) ? ~u : (u | 0x80000000u);
}
__device__ __forceinline__ float decf(u32 u) {
    return __uint_as_float((u & 0x80000000u) ? (u & 0x7fffffffu) : ~u);
}

// K1: h = x@W ; es/ed ; per-batch max(ed) ; hT hi/lo (transposed bf16 split).
__global__ __launch_bounds__(256, 2) void gat_k1(
    const float* __restrict__ x, const float* __restrict__ W, const float* __restrict__ a,
    u16* __restrict__ hT_hi, u16* __restrict__ hT_lo,
    float* __restrict__ es, float* __restrict__ ed, u32* __restrict__ edmax)
{
    const int tid  = threadIdx.x;
    const int lane = tid & 63;
    const int wid  = tid >> 6;
    const int rowbase = blockIdx.x * 16;
    const int b    = rowbase >> 11;
    const int col0 = rowbase & 2047;

    __shared__ float xs[16][64];
    __shared__ u16 lh[64][20];
    __shared__ u16 ll[64][20];

    {
        const float4 v = *reinterpret_cast<const float4*>(x + (size_t)rowbase * 64 + tid * 4);
        *reinterpret_cast<float4*>(&xs[0][0] + tid * 4) = v;
    }

    float Wc[64];
#pragma unroll
    for (int k = 0; k < 64; ++k) Wc[k] = W[k * 64 + lane];
    const float asrc = a[lane], adst = a[64 + lane];
    __syncthreads();

    float edm = -1e30f;
#pragma unroll
    for (int r = 0; r < 4; ++r) {
        const int row = wid * 4 + r;
        float acc = 0.f;
#pragma unroll
        for (int kq = 0; kq < 16; ++kq) {
            const float4 xv = *reinterpret_cast<const float4*>(&xs[row][kq * 4]);
            acc = fmaf(xv.x, Wc[kq * 4 + 0], acc);
            acc = fmaf(xv.y, Wc[kq * 4 + 1], acc);
            acc = fmaf(xv.z, Wc[kq * 4 + 2], acc);
            acc = fmaf(xv.w, Wc[kq * 4 + 3], acc);
        }
        float vs = acc * asrc, vd = acc * adst;
#pragma unroll
        for (int off = 32; off; off >>= 1) {
            vs += __shfl_xor(vs, off, 64);
            vd += __shfl_xor(vd, off, 64);
        }
        if (lane == 0) { es[rowbase + row] = vs; ed[rowbase + row] = vd; }
        edm = fmaxf(edm, vd);
        u16 hi = f2bf(acc);
        float lo = acc - bf2f(hi);
        lh[lane][row] = hi;
        ll[lane][row] = f2bf(lo);
    }
    if (lane == 0) atomicMax(edmax + b, encf(edm));
    __syncthreads();

    {
        const int d = tid >> 2, part = tid & 3;
        u32 h0 = lh[d][part*4+0] | ((u32)lh[d][part*4+1] << 16);
        u32 h1 = lh[d][part*4+2] | ((u32)lh[d][part*4+3] << 16);
        u32 l0 = ll[d][part*4+0] | ((u32)ll[d][part*4+1] << 16);
        u32 l1 = ll[d][part*4+2] | ((u32)ll[d][part*4+3] << 16);
        size_t goff = (size_t)(b * 64 + d) * 2048 + col0 + part * 4;
        *reinterpret_cast<uint2*>(hT_hi + goff) = make_uint2(h0, h1);
        *reinterpret_cast<uint2*>(hT_lo + goff) = make_uint2(l0, l1);
    }
}

#define NTL(p) __builtin_nontemporal_load(reinterpret_cast<const i32x4*>(p))

// one 32-col window; WQ/C are literal tokens -> all indexing compile-time
#define WIN_BODY(WQ, C, RA, RB)                                                   \
{                                                                                 \
    const int win = (WQ) * 4 + (C);                                               \
    const int av[8] = {RA[0], RA[1], RA[2], RA[3], RB[0], RB[1], RB[2], RB[3]};   \
    const float4 e0 = *reinterpret_cast<const float4*>(edq + win * 32);           \
    const float4 e1 = *reinterpret_cast<const float4*>(edq + win * 32 + 4);       \
    const float ev[8] = {e0.x, e0.y, e0.z, e0.w, e1.x, e1.y, e1.z, e1.w};         \
    float pe[8];                                                                  \
    _Pragma("unroll")                                                             \
    for (int q = 0; q < 8; ++q) {                                                 \
        const float tt = es_i + ev[q];                                            \
        const float eL = fmaxf(tt, 0.2f * tt);                                    \
        const float p  = __builtin_amdgcn_exp2f(fmaf(eL, L2E, -CL));              \
        pe[q] = av[q] ? p : 0.f;                                                  \
    }                                                                             \
    rs += ((pe[0]+pe[1]) + (pe[2]+pe[3])) + ((pe[4]+pe[5]) + (pe[6]+pe[7]));      \
    short8 pa;                                                                    \
    _Pragma("unroll")                                                             \
    for (int q = 0; q < 8; ++q) pa[q] = (short)f2bf(pe[q]);                       \
    const char* hb = smem + li * ROWB + win * 64 + lg * 16;                       \
    short8 f0h = *reinterpret_cast<const short8*>(hb + 0 * 16640);                \
    short8 f1h = *reinterpret_cast<const short8*>(hb + 1 * 16640);                \
    short8 f2h = *reinterpret_cast<const short8*>(hb + 2 * 16640);                \
    short8 f3h = *reinterpret_cast<const short8*>(hb + 3 * 16640);                \
    short8 f0l = *reinterpret_cast<const short8*>(hb + LO_OFF + 0 * 16640);       \
    short8 f1l = *reinterpret_cast<const short8*>(hb + LO_OFF + 1 * 16640);       \
    short8 f2l = *reinterpret_cast<const short8*>(hb + LO_OFF + 2 * 16640);       \
    short8 f3l = *reinterpret_cast<const short8*>(hb + LO_OFF + 3 * 16640);       \
    acc0 = __builtin_amdgcn_mfma_f32_16x16x32_bf16(pa, f0h, acc0, 0, 0, 0);       \
    acc1 = __builtin_amdgcn_mfma_f32_16x16x32_bf16(pa, f1h, acc1, 0, 0, 0);       \
    acc2 = __builtin_amdgcn_mfma_f32_16x16x32_bf16(pa, f2h, acc2, 0, 0, 0);       \
    acc3 = __builtin_amdgcn_mfma_f32_16x16x32_bf16(pa, f3h, acc3, 0, 0, 0);       \
    acc0 = __builtin_amdgcn_mfma_f32_16x16x32_bf16(pa, f0l, acc0, 0, 0, 0);       \
    acc1 = __builtin_amdgcn_mfma_f32_16x16x32_bf16(pa, f1l, acc1, 0, 0, 0);       \
    acc2 = __builtin_amdgcn_mfma_f32_16x16x32_bf16(pa, f2l, acc2, 0, 0, 0);       \
    acc3 = __builtin_amdgcn_mfma_f32_16x16x32_bf16(pa, f3l, acc3, 0, 0, 0);       \
    if ((WQ) < 3) {                                                               \
        RA = NTL(arow + (win + 4) * 32);                                          \
        RB = NTL(arow + (win + 4) * 32 + 4);                                      \
    }                                                                             \
}

// K3: block = 256 rows x 512 j; 16 waves, each owns 16 rows, NO barriers in
// the j-sweep. hT hi/lo staged once in LDS; adjacency via 4-deep register ring.
__global__ __launch_bounds__(1024, 4) void gat_k3(
    const int* __restrict__ adj,
    const u16* __restrict__ hT_hi, const u16* __restrict__ hT_lo,
    const float* __restrict__ es, const float* __restrict__ ed,
    const u32* __restrict__ edmax,
    float* __restrict__ acc_part, float* __restrict__ rs_part)
{
    __shared__ char smem[SMEM_SZ] __attribute__((aligned(16)));
    const int g  = blockIdx.x;
    const int b  = g & 7;                 // batch -> XCD pinned
    const int r2 = g >> 3;
    const int it = r2 & 7;                // 8 row-tiles of 256
    const int jc = r2 >> 3;               // 4 j-chunks of 512
    const int tid  = threadIdx.x;
    const int lane = tid & 63;
    const int w    = tid >> 6;            // 0..15
    const int li   = lane & 15;
    const int lg   = lane >> 4;
    const int gr0  = b * 2048 + it * 256;

    // ---- stage hT hi/lo slab (once) + ed chunk ----
#pragma unroll
    for (int rep = 0; rep < 4; ++rep) {
        const int idx  = rep * 1024 + tid;        // 0..4095
        const int half = idx >> 11;               // 0 hi, 1 lo
        const int rr   = idx & 2047;
        const int d    = rr >> 5;
        const int sg   = rr & 31;                 // 16 u16 each
        const u16* src = (half ? hT_lo : hT_hi) + (size_t)(b * 64 + d) * 2048
                       + jc * 512 + sg * 16;
        const uint4 v0 = *reinterpret_cast<const uint4*>(src);
        const uint4 v1 = *reinterpret_cast<const uint4*>(src + 8);
        char* dst = smem + half * LO_OFF + d * ROWB + sg * 32;
        *reinterpret_cast<uint4*>(dst)      = v0;
        *reinterpret_cast<uint4*>(dst + 16) = v1;
    }
    if (tid < 512)
        *((float*)(smem + ED_OFF) + tid) = ed[b * 2048 + jc * 512 + tid];

    const int row_g = gr0 + w * 16 + li;
    const float es_i = es[row_g];
    const float edM  = decf(edmax[b]);
    const float t0   = es_i + edM;
    const float Mi   = fmaxf(t0, 0.2f * t0);      // exact upper bound on row max
    const float L2E  = 1.44269504088896f;
    const float CL   = Mi * L2E;

    const int* __restrict__ arow = adj + (size_t)row_g * 2048 + jc * 512 + lg * 8;

    __syncthreads();   // slab ready; LAST barrier before epilogue

    const float* edq = (const float*)(smem + ED_OFF) + lg * 8;

    // adjacency ring: 4 windows deep, statically named slots
    i32x4 r0a = NTL(arow +  0), r0b = NTL(arow +   4);
    i32x4 r1a = NTL(arow + 32), r1b = NTL(arow +  36);
    i32x4 r2a = NTL(arow + 64), r2b = NTL(arow +  68);
    i32x4 r3a = NTL(arow + 96), r3b = NTL(arow + 100);

    f32x4 acc0 = {0.f,0.f,0.f,0.f}, acc1 = {0.f,0.f,0.f,0.f};
    f32x4 acc2 = {0.f,0.f,0.f,0.f}, acc3 = {0.f,0.f,0.f,0.f};
    float rs = 0.f;

    WIN_BODY(0, 0, r0a, r0b)  WIN_BODY(0, 1, r1a, r1b)
    WIN_BODY(0, 2, r2a, r2b)  WIN_BODY(0, 3, r3a, r3b)
    WIN_BODY(1, 0, r0a, r0b)  WIN_BODY(1, 1, r1a, r1b)
    WIN_BODY(1, 2, r2a, r2b)  WIN_BODY(1, 3, r3a, r3b)
    WIN_BODY(2, 0, r0a, r0b)  WIN_BODY(2, 1, r1a, r1b)
    WIN_BODY(2, 2, r2a, r2b)  WIN_BODY(2, 3, r3a, r3b)
    WIN_BODY(3, 0, r0a, r0b)  WIN_BODY(3, 1, r1a, r1b)
    WIN_BODY(3, 2, r2a, r2b)  WIN_BODY(3, 3, r3a, r3b)

    // ---- epilogue: per-wave direct partial write (no block sync needed) ----
    rs += __shfl_xor(rs, 16, 64);
    rs += __shfl_xor(rs, 32, 64);
    if (lane < 16)
        rs_part[(size_t)jc * 16384 + gr0 + w * 16 + li] = rs;

    f32x4 accs[4] = {acc0, acc1, acc2, acc3};
#pragma unroll
    for (int dt = 0; dt < 4; ++dt)
#pragma unroll
        for (int r = 0; r < 4; ++r)
            acc_part[((size_t)jc * 16384 + gr0 + w * 16 + 4 * lg + r) * 64
                     + dt * 16 + li] = accs[dt][r];
}

// K4: combine 4 j-chunks, normalize
__global__ __launch_bounds__(512) void gat_k4(
    const float4* __restrict__ ap, const float* __restrict__ rp,
    float4* __restrict__ out)
{
    const int idx = blockIdx.x * 512 + threadIdx.x;   // 0..262143 float4s
    const int row = idx >> 4;
    float4 s = ap[idx];
    const float4 u1 = ap[262144 + idx];
    const float4 u2 = ap[2 * 262144 + idx];
    const float4 u3 = ap[3 * 262144 + idx];
    s.x += u1.x + u2.x + u3.x;  s.y += u1.y + u2.y + u3.y;
    s.z += u1.z + u2.z + u3.z;  s.w += u1.w + u2.w + u3.w;
    const float inv = 1.0f / (rp[row] + rp[16384 + row]
                            + rp[2 * 16384 + row] + rp[3 * 16384 + row]);
    out[idx] = make_float4(s.x * inv, s.y * inv, s.z * inv, s.w * inv);
}

extern "C" void kernel_launch(void* const* d_in, const int* in_sizes, int n_in,
                              void* d_out, int out_size, void* d_ws, size_t ws_size,
                              hipStream_t stream)
{
    const float* x   = (const float*)d_in[0];
    const int*   adj = (const int*)d_in[1];
    const float* W   = (const float*)d_in[2];
    const float* a   = (const float*)d_in[3];
    float* out = (float*)d_out;

    char* ws = (char*)d_ws;
    size_t off = 0;
    auto carve = [&](size_t bytes) -> void* {
        void* p = ws + off;
        off += (bytes + 255) & ~(size_t)255;
        return p;
    };
    u16*   hT_hi    = (u16*)  carve((size_t)NB * 64 * NN * 2);
    u16*   hT_lo    = (u16*)  carve((size_t)NB * 64 * NN * 2);
    float* es       = (float*)carve((size_t)NB * NN * 4);
    float* ed       = (float*)carve((size_t)NB * NN * 4);
    u32*   edmax    = (u32*)  carve(256);
    float* acc_part = (float*)carve((size_t)4 * NB * NN * 64 * 4);  // 16 MB
    float* rs_part  = (float*)carve((size_t)4 * NB * NN * 4);       // 256 KB
    (void)ws_size; (void)in_sizes; (void)n_in; (void)out_size;

    hipMemsetAsync(edmax, 0, 256, stream);
    gat_k1<<<NB * NN / 16, 256, 0, stream>>>(x, W, a, hT_hi, hT_lo, es, ed, edmax);
    gat_k3<<<256, 1024, 0, stream>>>(adj, hT_hi, hT_lo, es, ed, edmax,
                                     acc_part, rs_part);
    gat_k4<<<512, 512, 0, stream>>>((const float4*)acc_part, rs_part, (float4*)out);
}